// Round 12
// baseline (46.865 us; speedup 1.0000x reference)
//
#include <hip/hip_runtime.h>

typedef float v4f __attribute__((ext_vector_type(4)));

// The 12 nonzero taps of the 23-tap halfband filter (even indices 0,2,..,22).
// The only other nonzero tap is the center (index 11) with weight 1.0 -> pure copy.
__device__ constexpr float W12[12] = {
    -1.20162964e-04f,    1.615524292e-03f, -1.0385513306e-02f,  4.3619155884e-02f,
    -1.45397186478e-01f, 6.1066818237e-01f, 6.1066818237e-01f, -1.45397186478e-01f,
     4.3619155884e-02f, -1.0385513306e-02f, 1.615524292e-03f,  -1.20162964e-04f
};

// Bijective XCD-chunking swizzle (grid % 8 == 0).
__device__ __forceinline__ int xcd_map(int bid, int nblk) {
    int cpx = nblk >> 3;
    return (bid & 7) * cpx + (bid >> 3);
}

// Fully fused 4x upsample: x[160x160] -> out[640x640] per slice, one kernel.
// Per block: out tile rows [2K0, 2K0+63] x cols [C0, C0+127], C0 = 2*MC0.
// Semantics verified R3-R11 (absmax 0.0156). R12: C/D split into interleaved
// halves (C1 | D1+C2 | D2) so HBM stores flow during ~45% of the block instead
// of the last 25% — D1 reads ew rows <=26 while C2 writes rows >=27 (disjoint,
// no barrier between them). All store instructions keep the coalesced layout
// (32 lanes x 16B = 512B contiguous; R10's lane-strided variant amplified 4x).
__global__ __launch_bounds__(256) void k_fused(const float* __restrict__ x,
                                               float* __restrict__ out) {
    __shared__ float xw[32][84];    // width1 rows (x-row resolution), +4 pad
    __shared__ float meb[21][84];   // even mid rows K0-4+2j, j=0..20
    __shared__ float ew[43][132];   // width2 rows (out-col resolution), +4 pad

    int bid = xcd_map(blockIdx.x, gridDim.x);
    int ct = bid % 5, rt = (bid / 5) % 10, bc = bid / 50;
    int K0  = rt * 32;      // mid/ew row tile base
    int MC0 = ct * 64;      // mid col base
    int XB  = K0 / 2 - 8;   // xw row window base (pre-mod, may be negative)
    int tid = threadIdx.x;

    // ---- Phase A: xw[e][:] = width1 of x row (XB+e mod 160), cols MC0-8..MC0+71.
    // filter: f[d] = sum_s W12[s]*flat[d+s+2]; copy col = flat[d+8].
#pragma unroll
    for (int it = 0; it < 2; ++it) {
        int idx = it * 256 + tid;
        int e = idx / 10, g = idx % 10;
        if (e < 32) {
            int m = XB + e;
            m = m < 0 ? m + 160 : (m >= 160 ? m - 160 : m);
            const float* xr = x + (bc * 160 + m) * 160;
            int qg = 8 * ct - 1 + g;       // global 8-col pair group (may be -1 or 40)
            int i0 = 4 * qg;
            float flat[20];
#pragma unroll
            for (int b = 0; b < 5; ++b) {
                int bq = qg - 2 + b; bq = bq < 0 ? 0 : (bq > 39 ? 39 : bq);
                *(v4f*)(flat + 4 * b) = *(const v4f*)(xr + 4 * bq);
            }
            if (ct == 0) {                 // left pad -> 0 (only possible here)
#pragma unroll
                for (int p = 2; p < 8; ++p) flat[p] = (i0 - 8 + p < 0) ? 0.f : flat[p];
            }
            float xlast = flat[19];        // = x[159] whenever right clamp occurred
            if (ct == 4) {                 // right pad -> x[159] (only possible here)
#pragma unroll
                for (int p = 12; p < 17; ++p) flat[p] = (i0 - 8 + p > 159) ? xlast : flat[p];
            }
            float f[4], cpy[4];
#pragma unroll
            for (int d = 0; d < 4; ++d) {
                float acc = 0.f;
#pragma unroll
                for (int s = 0; s < 12; ++s) acc += W12[s] * flat[d + s + 2];
                f[d] = acc;
                cpy[d] = flat[d + 8];
            }
            if (ct == 4 && i0 >= 151) {    // stage-1 right-edge copy correction
#pragma unroll
                for (int d = 0; d < 4; ++d) {
                    int i = i0 + d;
                    float c = 0.f;
#pragma unroll
                    for (int s = 0; s < 12; ++s) if (i + s >= 165) c += W12[s];
                    cpy[d] += c * xlast;
                }
            }
            v4f o0, o1;
            o0.x = f[0]; o0.y = cpy[0]; o0.z = f[1]; o0.w = cpy[1];
            o1.x = f[2]; o1.y = cpy[2]; o1.z = f[3]; o1.w = cpy[3];
            *(v4f*)(&xw[e][8 * g])     = o0;
            *(v4f*)(&xw[e][8 * g + 4]) = o1;
        }
    }
    __syncthreads();

    // ---- Phase B: meb rows in pairs (rows 2p, 2p+1 share 11 of 12 xw reads).
    {
        int p = tid / 20, lq = tid % 20;
        if (p < 11) {
            int rlast = 2 * p + 12; rlast = rlast < 32 ? rlast : 31;  // p=10: dummy
            v4f r[13];
#pragma unroll
            for (int s = 0; s < 12; ++s) r[s] = *(const v4f*)(&xw[2 * p + s][4 * lq]);
            r[12] = *(const v4f*)(&xw[rlast][4 * lq]);
            v4f a0 = {0.f, 0.f, 0.f, 0.f}, a1 = {0.f, 0.f, 0.f, 0.f};
#pragma unroll
            for (int s = 0; s < 12; ++s) {
                a0 += W12[s] * r[s];
                a1 += W12[s] * r[s + 1];
            }
            *(v4f*)(&meb[2 * p][4 * lq]) = a0;
            if (2 * p + 1 < 21) *(v4f*)(&meb[2 * p + 1][4 * lq]) = a1;
        }
    }
    __syncthreads();

    // ---- width2 row generator (verified R9-R11): ew[e][:] from xw/meb.
    // e even -> input = xw[e/2+5]; e odd -> input = meb[(e-1)/2].
    // flat[p] = local col 8h+p; f[d] = sum_s W12[s]*flat[d+s+3]; copy = flat[d+8].
    auto gen_ew = [&](int e, int h) {
        const float* row = (e & 1) ? &meb[(e - 1) / 2][0] : &xw[e / 2 + 5][0];
        float flat[24];
#pragma unroll
        for (int b = 0; b < 6; ++b)        // quads 2h..2h+5 (local cols 8h..8h+23)
            *(v4f*)(flat + 4 * b) = *(const v4f*)(row + 4 * (2 * h + b));
        float f[8], cpy[8];
        if (ct == 0 && h == 0) {           // left pad -> mid[0] + copy corr
            float m0 = row[8];             // local col 8 = global mid col 0
#pragma unroll
            for (int p = 3; p < 8; ++p) flat[p] = m0;   // cols -5..-1
#pragma unroll
            for (int d = 0; d < 8; ++d) {
                float acc = 0.f;
#pragma unroll
                for (int s = 0; s < 12; ++s) acc += W12[s] * flat[d + s + 3];
                f[d] = acc;
                cpy[d] = flat[d + 8];
            }
#pragma unroll
            for (int d = 0; d < 6; ++d) {  // i = d <= 5
                float c = 0.f;
#pragma unroll
                for (int s = 0; s < 12; ++s) if (d + s <= 5) c += W12[s];
                cpy[d] += c * m0;
            }
        } else {
            if (ct == 4 && h == 7) {       // right pad -> 0 (cols 320..)
#pragma unroll
                for (int p = 16; p < 24; ++p) flat[p] = 0.f;
            }
#pragma unroll
            for (int d = 0; d < 8; ++d) {
                float acc = 0.f;
#pragma unroll
                for (int s = 0; s < 12; ++s) acc += W12[s] * flat[d + s + 3];
                f[d] = acc;
                cpy[d] = flat[d + 8];
            }
        }
#pragma unroll
        for (int j = 0; j < 4; ++j) {
            v4f v;
            v.x = cpy[2 * j]; v.y = f[2 * j];
            v.z = cpy[2 * j + 1]; v.w = f[2 * j + 1];
            *(v4f*)(&ew[e][16 * h + 4 * j]) = v;
        }
    };

    // out-row emitter (coalesced: 32 lanes x 16B = 512B per instruction).
    int c4 = tid & 31, slot = tid >> 5;
    float* dbase = out + (size_t)bc * 640 * 640 + 2 * MC0 + 4 * c4;
    auto emit_pair = [&](const v4f* w, int kk) {
        // even out row 2(K0+kk) = ew[kk+5] = w[5]
        __builtin_nontemporal_store(w[5],
            (v4f*)(dbase + (size_t)(2 * (K0 + kk)) * 640));
        v4f acc = W12[0] * w[0];
#pragma unroll
        for (int s = 1; s < 12; ++s) acc += W12[s] * w[s];
        __builtin_nontemporal_store(acc,
            (v4f*)(dbase + (size_t)(2 * (K0 + kk) + 1) * 640));
    };

    // ---- Phase C1: ew rows 0..26 (216 items).
    {
        int e = tid >> 3, h = tid & 7;
        if (e < 27) gen_ew(e, h);
    }
    __syncthreads();

    // ---- Phase D1 + C2 (no barrier between: D1 reads ew<=26, C2 writes >=27).
    {
        // D1: kk = 2*slot + u (0..15); window ew[kk..kk+11] subset of 0..26.
        v4f w[12];
#pragma unroll
        for (int t = 0; t < 12; ++t) w[t] = *(const v4f*)(&ew[2 * slot + t][4 * c4]);
        emit_pair(w, 2 * slot);
#pragma unroll
        for (int t = 0; t < 11; ++t) w[t] = w[t + 1];
        w[11] = *(const v4f*)(&ew[2 * slot + 12][4 * c4]);
        emit_pair(w, 2 * slot + 1);
        // C2: ew rows 27..42 (128 items, threads 0..127).
        int e = 27 + (tid >> 3), h = tid & 7;
        if (e < 43) gen_ew(e, h);
    }
    __syncthreads();

    // ---- Phase D2: kk = 16 + 2*slot + u (16..31); window subset of 16..42.
    {
        v4f w[12];
#pragma unroll
        for (int t = 0; t < 12; ++t) w[t] = *(const v4f*)(&ew[16 + 2 * slot + t][4 * c4]);
        emit_pair(w, 16 + 2 * slot);
#pragma unroll
        for (int t = 0; t < 11; ++t) w[t] = w[t + 1];
        w[11] = *(const v4f*)(&ew[16 + 2 * slot + 12][4 * c4]);
        emit_pair(w, 16 + 2 * slot + 1);
    }
}

extern "C" void kernel_launch(void* const* d_in, const int* in_sizes, int n_in,
                              void* d_out, int out_size, void* d_ws, size_t ws_size,
                              hipStream_t stream) {
    const float* x = (const float*)d_in[0];
    float* out = (float*)d_out;
    // 6400 blocks = 128 bc x 10 row-tiles x 5 col-tiles (d_ws unused)
    k_fused<<<6400, 256, 0, stream>>>(x, out);
}

// Round 13
// 45.906 us; speedup vs baseline: 1.0209x; 1.0209x over previous
//
#include <hip/hip_runtime.h>

typedef float v4f __attribute__((ext_vector_type(4)));

// The 12 nonzero taps of the 23-tap halfband filter (even indices), center tap = 1.
constexpr float W12c[12] = {
    -1.20162964e-04f,    1.615524292e-03f, -1.0385513306e-02f,  4.3619155884e-02f,
    -1.45397186478e-01f, 6.1066818237e-01f, 6.1066818237e-01f, -1.45397186478e-01f,
     4.3619155884e-02f, -1.0385513306e-02f, 1.615524292e-03f,  -1.20162964e-04f
};

// Composite height weights over ww rows (ww = width-composited x rows).
// H1: mid[2m+1]=ww[m]; mid[2k]=sum_s W12[s] ww[k-6+s] (wrap).
// H2: out[2j]=mid[j]; out[2j+1]=sum_s W12[s] mid[j-5+s] (wrap).
// => out[4k]   = sum_u W12[u] ww[k-6+u]
//    out[4k+1] = sum_d ge[d] ww[k-8+d]   (j=2k:  s=2v copies d=v+5; s=2v+1 conv d=v+u)
//    out[4k+2] = ww[k]
//    out[4k+3] = sum_d go[d] ww[k-8+d]   (j=2k+1: s=2v+1 copies d=v+6; s=2v conv d=v+u)
struct GTabs { float ge[17]; float go[17]; };
constexpr GTabs make_gtabs() {
    GTabs t{};
    for (int d = 0; d < 17; ++d) { t.ge[d] = 0.f; t.go[d] = 0.f; }
    for (int v = 0; v < 6; ++v) { t.ge[v + 5] += W12c[2 * v]; t.go[v + 6] += W12c[2 * v + 1]; }
    for (int v = 0; v < 6; ++v)
        for (int u = 0; u < 12; ++u) {
            t.ge[v + u] += W12c[2 * v + 1] * W12c[u];
            t.go[v + u] += W12c[2 * v]     * W12c[u];
        }
    return t;
}
__device__ constexpr GTabs G = make_gtabs();

// Bijective XCD-chunking swizzle (grid % 8 == 0).
__device__ __forceinline__ int xcd_map(int bid, int nblk) {
    int cpx = nblk >> 3;
    return (bid & 7) * cpx + (bid >> 3);
}

// Fully fused, reordered 4x upsample: out = (H2 H1)(W2 W1)(x) — widths commute
// with heights (separate axes). Per block: out rows [4KQ, 4KQ+127] x cols
// [128ct, 128ct+127]. LDS = ww[48][132] = 25.3 KB. ONE barrier.
// Width semantics per row (verified R3-R12):
//  W1 (off=1): mid col 2u = sum_s W12[s] x[u-6+s] (L pad->0, R pad->x[159]);
//              mid col 2xi+1 = x[xi] + R-corr (sum_{s: xi+s>=165} W12[s] * x[159]).
//  W2 (off=0): ww col 2i = mid[i] + L-corr (i<=5: sum_{s:i+s<=5} W12[s]*mid[0]);
//              ww col 2i+1 = sum_s W12[s] mid[i-5+s] (L pad->mid[0], R pad->0).
__global__ __launch_bounds__(256) void k_fused(const float* __restrict__ x,
                                               float* __restrict__ out) {
    __shared__ float ww[48][132];   // rows (KQ-8 .. KQ+39) mod 160, 128 cols + pad

    int bid = xcd_map(blockIdx.x, gridDim.x);
    int ct = bid % 5, rt = (bid / 5) % 5, bc = bid / 25;
    int KQ = rt * 32;          // out-row quads KQ..KQ+31
    int MC0 = ct * 64;         // mid col base (out col base = 2*MC0)
    int WB = KQ - 8;           // ww row window base (pre-mod)
    int tid = threadIdx.x;

    // ---- Phase A': ww[e][:] = W2(W1(x row (WB+e) mod 160)), 16 out cols/item.
    // Item (e, g): out cols 16g..16g+15 <-> mid cols I0..I0+18, I0 = MC0+8g-5.
    // x window: XC0..XC0+19, XC0 = 32ct+4g-8 (4-aligned). flat[p] <-> x col XC0+p.
    // mid evens: mcol[2t+1] = me[t] = sum_s W12[s] flat[t+s]  (t=0..8)
    // mid odds (copies): mcol[2t] = flat[5+t] (+R-corr)       (t=0..9)
    // out: oe[d] = mcol[d+5] (+L-corr), oo[d] = sum_s W12[s] mcol[d+s] (d=0..7)
#pragma unroll
    for (int it = 0; it < 2; ++it) {
        int idx = it * 256 + tid;
        if (idx < 384) {
            int e = idx >> 3, g = idx & 7;
            int m = WB + e; m = m < 0 ? m + 160 : (m >= 160 ? m - 160 : m);
            const float* xr = x + (bc * 160 + m) * 160;
            int XC0 = 32 * ct + 4 * g - 8;
            int qb0 = (32 * ct + 4 * g - 8) >> 2;   // = XC0/4 (floor)
            float flat[20];
#pragma unroll
            for (int b = 0; b < 5; ++b) {
                int bq = qb0 + b; bq = bq < 0 ? 0 : (bq > 39 ? 39 : bq);
                *(v4f*)(flat + 4 * b) = *(const v4f*)(xr + 4 * bq);
            }
            if (ct == 0 && g < 2) {        // W1 left pad: cols < 0 -> 0
#pragma unroll
                for (int p = 0; p < 8; ++p) flat[p] = (XC0 + p < 0) ? 0.f : flat[p];
            }
            float x159 = flat[19];         // = x[159] whenever right clamp occurred
            if (ct == 4 && g >= 6) {       // W1 right pad: cols > 159 -> x[159]
#pragma unroll
                for (int p = 12; p < 20; ++p) flat[p] = (XC0 + p > 159) ? x159 : flat[p];
            }
            float mcol[19];
#pragma unroll
            for (int t = 0; t < 9; ++t) {  // evens: 12-tap W1
                float acc = 0.f;
#pragma unroll
                for (int s = 0; s < 12; ++s) acc += W12c[s] * flat[t + s];
                mcol[2 * t + 1] = acc;
            }
#pragma unroll
            for (int t = 0; t < 10; ++t) mcol[2 * t] = flat[5 + t];   // copies
            if (ct == 4 && g >= 5) {       // stage-1 right copy corr (xi >= 154)
#pragma unroll
                for (int t = 0; t < 10; ++t) {
                    int xi = XC0 + 5 + t;
                    float c = 0.f;
#pragma unroll
                    for (int s = 0; s < 12; ++s) if (xi + s >= 165) c += W12c[s];
                    mcol[2 * t] += c * x159;
                }
            }
            float mid0 = mcol[5];          // mid col I0+5 = global mid col 0 (g==0)
            if (ct == 0 && g == 0) {       // W2 left pad: mid cols < 0 -> mid[0]
#pragma unroll
                for (int p = 0; p < 5; ++p) mcol[p] = mid0;
            }
            if (ct == 4 && g == 7) {       // W2 right pad: mid cols > 319 -> 0
#pragma unroll
                for (int p = 13; p < 19; ++p) mcol[p] = 0.f;
            }
            float oe[8], oo[8];
#pragma unroll
            for (int d = 0; d < 8; ++d) {
                float acc = 0.f;
#pragma unroll
                for (int s = 0; s < 12; ++s) acc += W12c[s] * mcol[d + s];
                oo[d] = acc;
                oe[d] = mcol[d + 5];
            }
            if (ct == 0 && g == 0) {       // W2 left copy corr (i <= 5)
#pragma unroll
                for (int d = 0; d < 6; ++d) {
                    float c = 0.f;
#pragma unroll
                    for (int s = 0; s < 12; ++s) if (d + s <= 5) c += W12c[s];
                    oe[d] += c * mid0;
                }
            }
#pragma unroll
            for (int j = 0; j < 4; ++j) {
                v4f v;
                v.x = oe[2 * j];     v.y = oo[2 * j];
                v.z = oe[2 * j + 1]; v.w = oo[2 * j + 1];
                *(v4f*)(&ww[e][16 * g + 4 * j]) = v;
            }
        }
    }
    __syncthreads();

    // ---- Phase D': height composite. Sliding 17-row v4f window; 4 quads/thread.
    {
        int c4 = tid & 31, slot = tid >> 5;
        float* dbase = out + (size_t)bc * 640 * 640 + 2 * MC0 + 4 * c4;
        int eb = slot * 4;     // local quad base; window rows eb..eb+16 = k-8..k+8
        v4f w[17];
#pragma unroll
        for (int t = 0; t < 17; ++t) w[t] = *(const v4f*)(&ww[eb + t][4 * c4]);
#pragma unroll
        for (int q = 0; q < 4; ++q) {
            if (q > 0) {
#pragma unroll
                for (int t = 0; t < 16; ++t) w[t] = w[t + 1];
                w[16] = *(const v4f*)(&ww[eb + q + 16][4 * c4]);
            }
            int k = KQ + eb + q;
            float* r0 = dbase + (size_t)(4 * k) * 640;
            // out[4k] = 12-tap W12 over ww[k-6..k+5] = w[2..13]
            v4f a = W12c[0] * w[2];
#pragma unroll
            for (int u = 1; u < 12; ++u) a += W12c[u] * w[u + 2];
            __builtin_nontemporal_store(a, (v4f*)(r0));
            // out[4k+1] = ge over w[0..16]
            v4f b = G.ge[0] * w[0];
#pragma unroll
            for (int d = 1; d < 17; ++d) b += G.ge[d] * w[d];
            __builtin_nontemporal_store(b, (v4f*)(r0 + 640));
            // out[4k+2] = ww[k] = w[8]
            __builtin_nontemporal_store(w[8], (v4f*)(r0 + 1280));
            // out[4k+3] = go over w[0..16]
            v4f c = G.go[0] * w[0];
#pragma unroll
            for (int d = 1; d < 17; ++d) c += G.go[d] * w[d];
            __builtin_nontemporal_store(c, (v4f*)(r0 + 1920));
        }
    }
}

extern "C" void kernel_launch(void* const* d_in, const int* in_sizes, int n_in,
                              void* d_out, int out_size, void* d_ws, size_t ws_size,
                              hipStream_t stream) {
    const float* x = (const float*)d_in[0];
    float* out = (float*)d_out;
    // 3200 blocks = 128 bc x 5 row-tiles x 5 col-tiles (d_ws unused)
    k_fused<<<3200, 256, 0, stream>>>(x, out);
}

// Round 14
// 40.909 us; speedup vs baseline: 1.1456x; 1.1222x over previous
//
#include <hip/hip_runtime.h>

typedef float v4f __attribute__((ext_vector_type(4)));

// The 12 nonzero taps of the 23-tap halfband filter (even indices), center tap = 1.
constexpr float W12c[12] = {
    -1.20162964e-04f,    1.615524292e-03f, -1.0385513306e-02f,  4.3619155884e-02f,
    -1.45397186478e-01f, 6.1066818237e-01f, 6.1066818237e-01f, -1.45397186478e-01f,
     4.3619155884e-02f, -1.0385513306e-02f, 1.615524292e-03f,  -1.20162964e-04f
};

// Composite height weights over ww rows (ww = width-composited x rows).
// out[4k] = sum_u W12[u] ww[k-6+u]; out[4k+1] = sum_d ge[d] ww[k-8+d];
// out[4k+2] = ww[k];               out[4k+3] = sum_d go[d] ww[k-8+d].
struct GTabs { float ge[17]; float go[17]; };
constexpr GTabs make_gtabs() {
    GTabs t{};
    for (int d = 0; d < 17; ++d) { t.ge[d] = 0.f; t.go[d] = 0.f; }
    for (int v = 0; v < 6; ++v) { t.ge[v + 5] += W12c[2 * v]; t.go[v + 6] += W12c[2 * v + 1]; }
    for (int v = 0; v < 6; ++v)
        for (int u = 0; u < 12; ++u) {
            t.ge[v + u] += W12c[2 * v + 1] * W12c[u];
            t.go[v + u] += W12c[2 * v]     * W12c[u];
        }
    return t;
}
__device__ constexpr GTabs G = make_gtabs();

// Bijective XCD-chunking swizzle (grid % 8 == 0).
__device__ __forceinline__ int xcd_map(int bid, int nblk) {
    int cpx = nblk >> 3;
    return (bid & 7) * cpx + (bid >> 3);
}

// Fully fused, reordered 4x upsample: out = (H2 H1)(W2 W1)(x). R14 = R13 with
// PLAIN stores (no nontemporal): NT bypasses L2 write-combining, and our 512B
// per-instruction chunks (each 2560B row split over 5 same-XCD blocks) need L2
// to merge into full bursts. Fill kernel (plain, linear) runs 7 TB/s; our NT
// stores ran ~4.6 TB/s effective.
__global__ __launch_bounds__(256) void k_fused(const float* __restrict__ x,
                                               float* __restrict__ out) {
    __shared__ float ww[48][132];   // rows (KQ-8 .. KQ+39) mod 160, 128 cols + pad

    int bid = xcd_map(blockIdx.x, gridDim.x);
    int ct = bid % 5, rt = (bid / 5) % 5, bc = bid / 25;
    int KQ = rt * 32;          // out-row quads KQ..KQ+31
    int MC0 = ct * 64;         // mid col base (out col base = 2*MC0)
    int WB = KQ - 8;           // ww row window base (pre-mod)
    int tid = threadIdx.x;

    // ---- Phase A': ww[e][:] = W2(W1(x row (WB+e) mod 160)), 16 out cols/item.
#pragma unroll
    for (int it = 0; it < 2; ++it) {
        int idx = it * 256 + tid;
        if (idx < 384) {
            int e = idx >> 3, g = idx & 7;
            int m = WB + e; m = m < 0 ? m + 160 : (m >= 160 ? m - 160 : m);
            const float* xr = x + (bc * 160 + m) * 160;
            int XC0 = 32 * ct + 4 * g - 8;
            int qb0 = (32 * ct + 4 * g - 8) >> 2;   // = XC0/4 (floor)
            float flat[20];
#pragma unroll
            for (int b = 0; b < 5; ++b) {
                int bq = qb0 + b; bq = bq < 0 ? 0 : (bq > 39 ? 39 : bq);
                *(v4f*)(flat + 4 * b) = *(const v4f*)(xr + 4 * bq);
            }
            if (ct == 0 && g < 2) {        // W1 left pad: cols < 0 -> 0
#pragma unroll
                for (int p = 0; p < 8; ++p) flat[p] = (XC0 + p < 0) ? 0.f : flat[p];
            }
            float x159 = flat[19];         // = x[159] whenever right clamp occurred
            if (ct == 4 && g >= 6) {       // W1 right pad: cols > 159 -> x[159]
#pragma unroll
                for (int p = 12; p < 20; ++p) flat[p] = (XC0 + p > 159) ? x159 : flat[p];
            }
            float mcol[19];
#pragma unroll
            for (int t = 0; t < 9; ++t) {  // evens: 12-tap W1
                float acc = 0.f;
#pragma unroll
                for (int s = 0; s < 12; ++s) acc += W12c[s] * flat[t + s];
                mcol[2 * t + 1] = acc;
            }
#pragma unroll
            for (int t = 0; t < 10; ++t) mcol[2 * t] = flat[5 + t];   // copies
            if (ct == 4 && g >= 5) {       // stage-1 right copy corr (xi >= 154)
#pragma unroll
                for (int t = 0; t < 10; ++t) {
                    int xi = XC0 + 5 + t;
                    float c = 0.f;
#pragma unroll
                    for (int s = 0; s < 12; ++s) if (xi + s >= 165) c += W12c[s];
                    mcol[2 * t] += c * x159;
                }
            }
            float mid0 = mcol[5];          // mid col I0+5 = global mid col 0 (g==0)
            if (ct == 0 && g == 0) {       // W2 left pad: mid cols < 0 -> mid[0]
#pragma unroll
                for (int p = 0; p < 5; ++p) mcol[p] = mid0;
            }
            if (ct == 4 && g == 7) {       // W2 right pad: mid cols > 319 -> 0
#pragma unroll
                for (int p = 13; p < 19; ++p) mcol[p] = 0.f;
            }
            float oe[8], oo[8];
#pragma unroll
            for (int d = 0; d < 8; ++d) {
                float acc = 0.f;
#pragma unroll
                for (int s = 0; s < 12; ++s) acc += W12c[s] * mcol[d + s];
                oo[d] = acc;
                oe[d] = mcol[d + 5];
            }
            if (ct == 0 && g == 0) {       // W2 left copy corr (i <= 5)
#pragma unroll
                for (int d = 0; d < 6; ++d) {
                    float c = 0.f;
#pragma unroll
                    for (int s = 0; s < 12; ++s) if (d + s <= 5) c += W12c[s];
                    oe[d] += c * mid0;
                }
            }
#pragma unroll
            for (int j = 0; j < 4; ++j) {
                v4f v;
                v.x = oe[2 * j];     v.y = oo[2 * j];
                v.z = oe[2 * j + 1]; v.w = oo[2 * j + 1];
                *(v4f*)(&ww[e][16 * g + 4 * j]) = v;
            }
        }
    }
    __syncthreads();

    // ---- Phase D': height composite. Sliding 17-row v4f window; 4 quads/thread.
    {
        int c4 = tid & 31, slot = tid >> 5;
        float* dbase = out + (size_t)bc * 640 * 640 + 2 * MC0 + 4 * c4;
        int eb = slot * 4;     // local quad base; window rows eb..eb+16 = k-8..k+8
        v4f w[17];
#pragma unroll
        for (int t = 0; t < 17; ++t) w[t] = *(const v4f*)(&ww[eb + t][4 * c4]);
#pragma unroll
        for (int q = 0; q < 4; ++q) {
            if (q > 0) {
#pragma unroll
                for (int t = 0; t < 16; ++t) w[t] = w[t + 1];
                w[16] = *(const v4f*)(&ww[eb + q + 16][4 * c4]);
            }
            int k = KQ + eb + q;
            float* r0 = dbase + (size_t)(4 * k) * 640;
            // out[4k] = 12-tap W12 over ww[k-6..k+5] = w[2..13]
            v4f a = W12c[0] * w[2];
#pragma unroll
            for (int u = 1; u < 12; ++u) a += W12c[u] * w[u + 2];
            *(v4f*)(r0) = a;
            // out[4k+1] = ge over w[0..16]
            v4f b = G.ge[0] * w[0];
#pragma unroll
            for (int d = 1; d < 17; ++d) b += G.ge[d] * w[d];
            *(v4f*)(r0 + 640) = b;
            // out[4k+2] = ww[k] = w[8]
            *(v4f*)(r0 + 1280) = w[8];
            // out[4k+3] = go over w[0..16]
            v4f c = G.go[0] * w[0];
#pragma unroll
            for (int d = 1; d < 17; ++d) c += G.go[d] * w[d];
            *(v4f*)(r0 + 1920) = c;
        }
    }
}

extern "C" void kernel_launch(void* const* d_in, const int* in_sizes, int n_in,
                              void* d_out, int out_size, void* d_ws, size_t ws_size,
                              hipStream_t stream) {
    const float* x = (const float*)d_in[0];
    float* out = (float*)d_out;
    // 3200 blocks = 128 bc x 5 row-tiles x 5 col-tiles (d_ws unused)
    k_fused<<<3200, 256, 0, stream>>>(x, out);
}